// Round 2
// baseline (122.439 us; speedup 1.0000x reference)
//
#include <hip/hip_runtime.h>
#include <math.h>

#define C_CH 256
#define T_LEN 4096

// R15 = R14 (121.9us) + barrier-free conv in drive.
// - Old structure serialized {load row -> __syncthreads() -> consume} x3;
//   each barrier emits s_waitcnt vmcnt(0) so every block paid 3 serial
//   HBM/L2 latency rounds. Block == full row (512*8=4096=T), so each
//   thread's window [t0-4,t0+12) is 4 ALIGNED float4s loaded straight from
//   global (halo bytes come from L1/L2). sHalo (32KB LDS) and the 3 conv
//   barriers are gone; all 12 loads (3 rows x 4 float4) issue up-front, so
//   the single sWF barrier's vmcnt(0) drain is ONE parallel latency round.
// - Edge lanes: tid==0 zeroes xa[0..3], tid==511 zeroes xa[12..15], with
//   address clamps so no OOB byte is touched. FMA order identical to R14
//   (k ascending, rows ascending, same d init) -> bitwise-equal output.
// - VGPR budget: 48 load regs + d[8] + addr ~= 60, targeting the 64-reg
//   budget of __launch_bounds__(512,8). If this spills, revisit first.
// - Fusion remains dead (R3/R4/R12): cross-XCD producer->consumer costs
//   60-100us; kernel boundary is the only cheap sync.

#define LOAD_ROW(xa, r) do {                                                  \
    const int src_ = (jj + (r)) & 255;                                        \
    const float4* p_ = (const float4*)(x + ((size_t)b * C_CH + src_) * T_LEN + t0); \
    float4 qm_ = tid ? p_[-1] : p_[0];                                        \
    float4 q0_ = p_[0], q1_ = p_[1];                                          \
    float4 q2_ = (tid < 511) ? p_[2] : p_[1];                                 \
    if (tid == 0)   qm_ = make_float4(0.f, 0.f, 0.f, 0.f);                    \
    if (tid == 511) q2_ = make_float4(0.f, 0.f, 0.f, 0.f);                    \
    xa[0]  = qm_.x; xa[1]  = qm_.y; xa[2]  = qm_.z; xa[3]  = qm_.w;           \
    xa[4]  = q0_.x; xa[5]  = q0_.y; xa[6]  = q0_.z; xa[7]  = q0_.w;           \
    xa[8]  = q1_.x; xa[9]  = q1_.y; xa[10] = q1_.z; xa[11] = q1_.w;           \
    xa[12] = q2_.x; xa[13] = q2_.y; xa[14] = q2_.z; xa[15] = q2_.w;           \
} while (0)

__global__ __launch_bounds__(512, 8) void drive_scan_kernel(
    const float* __restrict__ x,
    const float* __restrict__ w3, const float* __restrict__ b3,
    const float* __restrict__ w5, const float* __restrict__ b5,
    const float* __restrict__ w9, const float* __restrict__ b9,
    const float* __restrict__ w_red, const float* __restrict__ b_red,
    const float* __restrict__ latency_scale,
    const float* __restrict__ og, const float* __restrict__ W1,
    const float* __restrict__ W2, float* __restrict__ ogT,
    float* __restrict__ sink,
    float* __restrict__ out_lat, float* __restrict__ out_act)
{
    const int blk = blockIdx.x;
    const int tid = threadIdx.x;

    if (blk < 8) {
        // --- og^T build (mlp reads it coalesced) + LLC warm of W1/W2,
        //     overlapped with the drive phase head ---
        const int id = blk * 512 + tid;            // 0..4095
        const float4* og4 = (const float4*)og;     // 16384 float4 (256x256)
        const float4* W14 = (const float4*)W1;     // 8192 float4
        const float4* W24 = (const float4*)W2;     // 8192 float4
        const int jrow  = id >> 4;                 // og row this thread copies
        const int ibase = (id & 15) << 4;          // first col of its 16 elems
        #pragma unroll
        for (int v = 0; v < 4; ++v) {
            float4 q = og4[id * 4 + v];            // og[jrow][ibase+4v .. +3]
            const int i = ibase + v * 4;
            ogT[(i + 0) * 256 + jrow] = q.x;
            ogT[(i + 1) * 256 + jrow] = q.y;
            ogT[(i + 2) * 256 + jrow] = q.z;
            ogT[(i + 3) * 256 + jrow] = q.w;
        }
        float acc = 0.0f;
        #pragma unroll
        for (int v = 0; v < 2; ++v) {
            float4 q = W14[id + v * 4096]; acc += q.x + q.y + q.z + q.w;
        }
        #pragma unroll
        for (int v = 0; v < 2; ++v) {
            float4 q = W24[id + v * 4096]; acc += q.x + q.y + q.z + q.w;
        }
        sink[id] = acc;                            // keep W1/W2 loads alive
        return;
    }

    const int bb   = blk - 8;
    const int b    = bb >> 8;
    const int i255 = bb & 255;
    // XCD-contiguous band index (dispatch round-robins blk % 8 across XCDs)
    const int jj   = ((i255 & 7) << 5) | (i255 >> 3);
    const int c    = (171 * jj) & 255;             // channel: 3*c = jj mod 256
    const int lane = tid & 63;
    const int wv   = tid >> 6;                     // 0..7

    __shared__ float sWF[28];                      // 27 folded taps + Beff
    __shared__ float sWaveTot[8];
    __shared__ float sCarry[8];
    __shared__ int   sMin[8];

    const int t0 = tid << 3;                       // this thread's 8 steps

    // --- issue ALL conv loads up-front: 3 rows x 4 aligned float4 ---
    float xa0[16], xa1[16], xa2[16];
    LOAD_ROW(xa0, 0);
    LOAD_ROW(xa1, 1);
    LOAD_ROW(xa2, 2);

    // --- parallel in-block weight fold (threads 0..27) ---
    if (tid < 27) {
        const int r = tid / 9, k = tid - 9 * r;
        const int q0     = 18 * c + 6 * r;
        const int region = (q0 >= 1536) + (q0 >= 3072);
        const int p0     = q0 - region * 1536;
        const int K      = (region == 0) ? 3 : (region == 1 ? 5 : 9);
        const int off    = (9 - K) >> 1;
        const float* wP  = (region == 0) ? w3 : (region == 1 ? w5 : w9);
        const int kk     = k - off;
        float w = 0.0f;
        if (kk >= 0 && kk < K) {
            const float* wr = w_red + c * 18 + 6 * r;
            #pragma unroll
            for (int j = 0; j < 6; ++j)
                w = fmaf(wr[j], wP[(p0 + j) * K + kk], w);
        }
        sWF[tid] = w;
    } else if (tid == 27) {
        float acc = b_red[c];
        #pragma unroll
        for (int r = 0; r < 3; ++r) {
            const int q0     = 18 * c + 6 * r;
            const int region = (q0 >= 1536) + (q0 >= 3072);
            const int p0     = q0 - region * 1536;
            const float* bP  = (region == 0) ? b3 : (region == 1 ? b5 : b9);
            const float* wr  = w_red + c * 18 + 6 * r;
            #pragma unroll
            for (int j = 0; j < 6; ++j) acc = fmaf(wr[j], bP[p0 + j], acc);
        }
        sWF[27] = acc;
    }

    __syncthreads();   // publishes sWF; also the single vmcnt drain for loads

    // --- 27-tap FMA into d[8]; same order as R14 -> bitwise equal ---
    float d[8];
    {
        const float Beff = sWF[27];
        #pragma unroll
        for (int tt = 0; tt < 8; ++tt) d[tt] = Beff;
    }
    #pragma unroll
    for (int k = 0; k < 9; ++k) {
        const float wk = sWF[k];
        #pragma unroll
        for (int tt = 0; tt < 8; ++tt)
            d[tt] = fmaf(wk, xa0[tt + k], d[tt]);
    }
    #pragma unroll
    for (int k = 0; k < 9; ++k) {
        const float wk = sWF[9 + k];
        #pragma unroll
        for (int tt = 0; tt < 8; ++tt)
            d[tt] = fmaf(wk, xa1[tt + k], d[tt]);
    }
    #pragma unroll
    for (int k = 0; k < 9; ++k) {
        const float wk = sWF[18 + k];
        #pragma unroll
        for (int tt = 0; tt < 8; ++tt)
            d[tt] = fmaf(wk, xa2[tt + k], d[tt]);
    }

    const float A   = (float)0.8187307530779818;          // exp(-1/5), fp32
    const float OMA = (float)(1.0 - 0.8187307530779818);  // matches ref rounding

    // --- chunk-local scan: V after 8 steps from 0 ---
    float S = 0.0f;
    #pragma unroll
    for (int tt = 0; tt < 8; ++tt) S = A * S + OMA * d[tt];

    // --- wave-level weighted inclusive scan (per-chunk decay A^8) ---
    const float Fp[6] = {
        (float)2.0189651799465541e-01,  // A^8   = e^-1.6
        (float)4.0762203978366215e-02,  // A^16
        (float)1.6615572731739337e-03,  // A^32
        (float)2.7607725720371943e-06,  // A^64
        (float)7.6218649302532563e-12,  // A^128
        (float)5.8092835977683129e-23   // A^256
    };
    float cinc = S;
    #pragma unroll
    for (int s = 0; s < 6; ++s) {
        const int o = 1 << s;
        const float y = __shfl_up(cinc, o, 64);
        if (lane >= o) cinc = fmaf(Fp[s], y, cinc);
    }
    if (lane == 63) sWaveTot[wv] = cinc;
    __syncthreads();
    if (tid == 0) {
        // cross-wave decay A^512 ~ 3.4e-45 (denormal ~ 0)
        const float A512 = 3.3744728758705166e-45f;
        float g = 0.0f;
        #pragma unroll
        for (int w = 0; w < 8; ++w) { sCarry[w] = g; g = sWaveTot[w] + A512 * g; }
    }
    __syncthreads();
    const float cprev = __shfl_up(cinc, 1, 64);
    const float Vin = (lane ? cprev : 0.0f)
                    + expf(-1.6f * (float)lane) * sCarry[wv];

    // --- replay chunk with true incoming V; first threshold crossing ---
    float V = Vin;
    int firstT = T_LEN;
    #pragma unroll
    for (int tt = 0; tt < 8; ++tt) {
        V = A * V + OMA * d[tt];
        if (V >= 1.0f && firstT == T_LEN) firstT = t0 + tt;
    }

    // --- block min-reduce ---
    #pragma unroll
    for (int o = 32; o > 0; o >>= 1)
        firstT = min(firstT, __shfl_xor(firstT, o, 64));
    if (lane == 0) sMin[wv] = firstT;
    __syncthreads();
    if (tid == 0) {
        int f = sMin[0];
        #pragma unroll
        for (int w = 1; w < 8; ++w) f = min(f, sMin[w]);
        const float lat   = (float)f;                          // T if never fired
        const float scale = fmaxf(latency_scale[0], 0.001f);
        out_lat[(b << 8) + c] = lat;
        out_act[(b << 8) + c] = expf(-lat / scale);
    }
}

// ---------------------------------------------------------------------------
// K2: gated mix + 2-layer MLP + softplus/clip. One 512-thread block per
// batch row. Mix phase reads precomputed ogT (coalesced over j), single
// serial fmaf chain per g-half preserving the previous accumulation order
// bitwise. W1/W2 phases: split reductions, 1-2 latency rounds each.
// Weights LLC-warm from the drive-phase warm-up blocks.
// ---------------------------------------------------------------------------
__global__ __launch_bounds__(512) void mlp_kernel(
    const float* __restrict__ act,
    const float* __restrict__ ogT, const float* __restrict__ bias,
    const float* __restrict__ W1, const float* __restrict__ b1,
    const float* __restrict__ W2, const float* __restrict__ b2,
    float* __restrict__ out_pred)
{
    const int b = blockIdx.x;
    const int t = threadIdx.x;
    const int j = t & 255;             // output index for og/W2 phases
    const int g = t >> 8;              // reduction group 0/1

    __shared__ float sAct[256];
    __shared__ float sP[2][256];       // og partials
    __shared__ float sMix[256];
    __shared__ float sPH[4][128];      // W1 partials
    __shared__ float sH[128];
    __shared__ float sPR[2][256];      // W2 partials

    if (t < 256) sAct[t] = act[b * 256 + t];
    __syncthreads();

    // mixed[j] = bias[j] + sum_i act[i]*og[j,i]; group g covers
    // i in [g*128, g*128+128). ogT[i*256+j] is coalesced over j.
    float mix = 0.0f;
    {
        const float* col = ogT + (size_t)(g * 128) * 256 + j;
        const float* a   = sAct + g * 128;
        #pragma unroll 16
        for (int ii = 0; ii < 128; ++ii)
            mix = fmaf(a[ii], col[ii * 256], mix);
    }
    sP[g][j] = mix;
    __syncthreads();
    if (t < 256) sMix[t] = bias[t] + sP[0][t] + sP[1][t];
    __syncthreads();

    // h[j1] = relu(b1 + sum_i mixed[i]*W1[i,j1]); 4 partials per j1, each a
    // fully-unrolled 64-load round. W1 (256,128) row-major: coalesced.
    {
        const int j1  = t & 127;
        const int seg = t >> 7;        // 0..3
        float h = 0.0f;
        #pragma unroll
        for (int ii = 0; ii < 64; ++ii) {
            const int i = seg * 64 + ii;
            h = fmaf(sMix[i], W1[i * 128 + j1], h);
        }
        sPH[seg][j1] = h;
    }
    __syncthreads();
    if (t < 128)
        sH[t] = fmaxf(b1[t] + ((sPH[0][t] + sPH[1][t]) + (sPH[2][t] + sPH[3][t])), 0.0f);
    __syncthreads();

    // raw[j] = b2[j] + sum_k h[k]*W2[k,j]; 2 partials per j, 64-load rounds.
    {
        float raw = 0.0f;
        #pragma unroll
        for (int kk = 0; kk < 64; ++kk) {
            const int k = g * 64 + kk;
            raw = fmaf(sH[k], W2[k * 256 + j], raw);
        }
        sPR[g][j] = raw;
    }
    __syncthreads();
    if (t < 256) {
        const float r  = b2[t] + sPR[0][t] + sPR[1][t];
        const float sp = fmaxf(r, 0.0f) + log1pf(expf(-fabsf(r)));
        out_pred[b * 256 + t] = fminf(fmaxf(sp, 0.0f), 4096.0f);
    }
}

// ---------------------------------------------------------------------------
extern "C" void kernel_launch(void* const* d_in, const int* in_sizes, int n_in,
                              void* d_out, int out_size, void* d_ws, size_t ws_size,
                              hipStream_t stream) {
    const float* x    = (const float*)d_in[0];
    const float* w3   = (const float*)d_in[1];
    const float* b3   = (const float*)d_in[2];
    const float* w5   = (const float*)d_in[3];
    const float* b5   = (const float*)d_in[4];
    const float* w9   = (const float*)d_in[5];
    const float* b9   = (const float*)d_in[6];
    const float* wred = (const float*)d_in[7];
    const float* bred = (const float*)d_in[8];
    const float* ls   = (const float*)d_in[9];
    const float* og   = (const float*)d_in[10];
    const float* bias = (const float*)d_in[11];
    const float* W1   = (const float*)d_in[12];
    const float* b1   = (const float*)d_in[13];
    const float* W2   = (const float*)d_in[14];
    const float* b2   = (const float*)d_in[15];

    float* ogT      = (float*)d_ws;           // 65536 floats (256KB)
    float* sink     = (float*)d_ws + 65536;   // prefetch sink (4096 floats)
    float* out      = (float*)d_out;
    float* out_pred = out;              // (8,256)
    float* out_lat  = out + 2048;       // (8,256)
    float* out_act  = out + 4096;       // (8,256)

    drive_scan_kernel<<<2056, 512, 0, stream>>>(
        x, w3, b3, w5, b5, w9, b9, wred, bred, ls,
        og, W1, W2, ogT, sink, out_lat, out_act);
    mlp_kernel<<<8, 512, 0, stream>>>(out_act, ogT, bias, W1, b1, W2, b2, out_pred);
}

// Round 4
// 119.658 us; speedup vs baseline: 1.0232x; 1.0232x over previous
//
#include <hip/hip_runtime.h>
#include <math.h>

#define C_CH 256
#define T_LEN 4096

// R17 = R16 resubmitted verbatim (R16 bench died to a container failure,
// not a kernel error; theory untested).
// R16 = R15 (122.4us) with the spill fixed + fold-first load ordering.
// - R15 post-mortem: removing 2 of 3 barrier latency rounds was NEUTRAL.
//   Candidate cause: R15 keeps 48 load VGPRs (xa0..xa2) live across the
//   barrier under __launch_bounds__(512,8)'s 64-VGPR cap -> scratch spills
//   on the hot path cancel the barrier win. R16 relaxes to (512,4) = 128
//   VGPRs, 2 blocks/CU resident (16 waves/CU) -- still enough TLP to cover
//   the single remaining load round.
// - Weight-fold scalar loads now issue BEFORE the 12 bulk float4s: vmcnt is
//   FIFO, so the fold's dependent chain (feeding the barrier all 512
//   threads wait on) no longer drains behind the bulk loads.
// - Math order unchanged everywhere -> bitwise-equal output (absmax 0.0).
// - If this round is ALSO neutral: timed window is fixed-cost dominated
//   (43us 256MiB ws poison fill + dozens of reset memsets); declare floor.
// - Fusion remains dead (R3/R4/R12): cross-XCD producer->consumer costs
//   60-100us; kernel boundary is the only cheap sync.

#define LOAD_ROW(xa, r) do {                                                  \
    const int src_ = (jj + (r)) & 255;                                        \
    const float4* p_ = (const float4*)(x + ((size_t)b * C_CH + src_) * T_LEN + t0); \
    float4 qm_ = tid ? p_[-1] : p_[0];                                        \
    float4 q0_ = p_[0], q1_ = p_[1];                                          \
    float4 q2_ = (tid < 511) ? p_[2] : p_[1];                                 \
    if (tid == 0)   qm_ = make_float4(0.f, 0.f, 0.f, 0.f);                    \
    if (tid == 511) q2_ = make_float4(0.f, 0.f, 0.f, 0.f);                    \
    xa[0]  = qm_.x; xa[1]  = qm_.y; xa[2]  = qm_.z; xa[3]  = qm_.w;           \
    xa[4]  = q0_.x; xa[5]  = q0_.y; xa[6]  = q0_.z; xa[7]  = q0_.w;           \
    xa[8]  = q1_.x; xa[9]  = q1_.y; xa[10] = q1_.z; xa[11] = q1_.w;           \
    xa[12] = q2_.x; xa[13] = q2_.y; xa[14] = q2_.z; xa[15] = q2_.w;           \
} while (0)

__global__ __launch_bounds__(512, 4) void drive_scan_kernel(
    const float* __restrict__ x,
    const float* __restrict__ w3, const float* __restrict__ b3,
    const float* __restrict__ w5, const float* __restrict__ b5,
    const float* __restrict__ w9, const float* __restrict__ b9,
    const float* __restrict__ w_red, const float* __restrict__ b_red,
    const float* __restrict__ latency_scale,
    const float* __restrict__ og, const float* __restrict__ W1,
    const float* __restrict__ W2, float* __restrict__ ogT,
    float* __restrict__ sink,
    float* __restrict__ out_lat, float* __restrict__ out_act)
{
    const int blk = blockIdx.x;
    const int tid = threadIdx.x;

    if (blk < 8) {
        // --- og^T build (mlp reads it coalesced) + LLC warm of W1/W2,
        //     overlapped with the drive phase head ---
        const int id = blk * 512 + tid;            // 0..4095
        const float4* og4 = (const float4*)og;     // 16384 float4 (256x256)
        const float4* W14 = (const float4*)W1;     // 8192 float4
        const float4* W24 = (const float4*)W2;     // 8192 float4
        const int jrow  = id >> 4;                 // og row this thread copies
        const int ibase = (id & 15) << 4;          // first col of its 16 elems
        #pragma unroll
        for (int v = 0; v < 4; ++v) {
            float4 q = og4[id * 4 + v];            // og[jrow][ibase+4v .. +3]
            const int i = ibase + v * 4;
            ogT[(i + 0) * 256 + jrow] = q.x;
            ogT[(i + 1) * 256 + jrow] = q.y;
            ogT[(i + 2) * 256 + jrow] = q.z;
            ogT[(i + 3) * 256 + jrow] = q.w;
        }
        float acc = 0.0f;
        #pragma unroll
        for (int v = 0; v < 2; ++v) {
            float4 q = W14[id + v * 4096]; acc += q.x + q.y + q.z + q.w;
        }
        #pragma unroll
        for (int v = 0; v < 2; ++v) {
            float4 q = W24[id + v * 4096]; acc += q.x + q.y + q.z + q.w;
        }
        sink[id] = acc;                            // keep W1/W2 loads alive
        return;
    }

    const int bb   = blk - 8;
    const int b    = bb >> 8;
    const int i255 = bb & 255;
    // XCD-contiguous band index (dispatch round-robins blk % 8 across XCDs)
    const int jj   = ((i255 & 7) << 5) | (i255 >> 3);
    const int c    = (171 * jj) & 255;             // channel: 3*c = jj mod 256
    const int lane = tid & 63;
    const int wv   = tid >> 6;                     // 0..7

    __shared__ float sWF[28];                      // 27 folded taps + Beff
    __shared__ float sWaveTot[8];
    __shared__ float sCarry[8];
    __shared__ int   sMin[8];

    const int t0 = tid << 3;                       // this thread's 8 steps

    // --- parallel in-block weight fold FIRST (threads 0..27): its dependent
    //     scalar-load chain feeds the barrier, so it must not queue behind
    //     the bulk loads (vmcnt drains FIFO) ---
    if (tid < 27) {
        const int r = tid / 9, k = tid - 9 * r;
        const int q0     = 18 * c + 6 * r;
        const int region = (q0 >= 1536) + (q0 >= 3072);
        const int p0     = q0 - region * 1536;
        const int K      = (region == 0) ? 3 : (region == 1 ? 5 : 9);
        const int off    = (9 - K) >> 1;
        const float* wP  = (region == 0) ? w3 : (region == 1 ? w5 : w9);
        const int kk     = k - off;
        float w = 0.0f;
        if (kk >= 0 && kk < K) {
            const float* wr = w_red + c * 18 + 6 * r;
            #pragma unroll
            for (int j = 0; j < 6; ++j)
                w = fmaf(wr[j], wP[(p0 + j) * K + kk], w);
        }
        sWF[tid] = w;
    } else if (tid == 27) {
        float acc = b_red[c];
        #pragma unroll
        for (int r = 0; r < 3; ++r) {
            const int q0     = 18 * c + 6 * r;
            const int region = (q0 >= 1536) + (q0 >= 3072);
            const int p0     = q0 - region * 1536;
            const float* bP  = (region == 0) ? b3 : (region == 1 ? b5 : b9);
            const float* wr  = w_red + c * 18 + 6 * r;
            #pragma unroll
            for (int j = 0; j < 6; ++j) acc = fmaf(wr[j], bP[p0 + j], acc);
        }
        sWF[27] = acc;
    }

    // --- issue ALL conv loads: 3 rows x 4 aligned float4 ---
    float xa0[16], xa1[16], xa2[16];
    LOAD_ROW(xa0, 0);
    LOAD_ROW(xa1, 1);
    LOAD_ROW(xa2, 2);

    __syncthreads();   // publishes sWF; single vmcnt drain for all loads

    // --- 27-tap FMA into d[8]; same order as R14/R15 -> bitwise equal ---
    float d[8];
    {
        const float Beff = sWF[27];
        #pragma unroll
        for (int tt = 0; tt < 8; ++tt) d[tt] = Beff;
    }
    #pragma unroll
    for (int k = 0; k < 9; ++k) {
        const float wk = sWF[k];
        #pragma unroll
        for (int tt = 0; tt < 8; ++tt)
            d[tt] = fmaf(wk, xa0[tt + k], d[tt]);
    }
    #pragma unroll
    for (int k = 0; k < 9; ++k) {
        const float wk = sWF[9 + k];
        #pragma unroll
        for (int tt = 0; tt < 8; ++tt)
            d[tt] = fmaf(wk, xa1[tt + k], d[tt]);
    }
    #pragma unroll
    for (int k = 0; k < 9; ++k) {
        const float wk = sWF[18 + k];
        #pragma unroll
        for (int tt = 0; tt < 8; ++tt)
            d[tt] = fmaf(wk, xa2[tt + k], d[tt]);
    }

    const float A   = (float)0.8187307530779818;          // exp(-1/5), fp32
    const float OMA = (float)(1.0 - 0.8187307530779818);  // matches ref rounding

    // --- chunk-local scan: V after 8 steps from 0 ---
    float S = 0.0f;
    #pragma unroll
    for (int tt = 0; tt < 8; ++tt) S = A * S + OMA * d[tt];

    // --- wave-level weighted inclusive scan (per-chunk decay A^8) ---
    const float Fp[6] = {
        (float)2.0189651799465541e-01,  // A^8   = e^-1.6
        (float)4.0762203978366215e-02,  // A^16
        (float)1.6615572731739337e-03,  // A^32
        (float)2.7607725720371943e-06,  // A^64
        (float)7.6218649302532563e-12,  // A^128
        (float)5.8092835977683129e-23   // A^256
    };
    float cinc = S;
    #pragma unroll
    for (int s = 0; s < 6; ++s) {
        const int o = 1 << s;
        const float y = __shfl_up(cinc, o, 64);
        if (lane >= o) cinc = fmaf(Fp[s], y, cinc);
    }
    if (lane == 63) sWaveTot[wv] = cinc;
    __syncthreads();
    if (tid == 0) {
        // cross-wave decay A^512 ~ 3.4e-45 (denormal ~ 0)
        const float A512 = 3.3744728758705166e-45f;
        float g = 0.0f;
        #pragma unroll
        for (int w = 0; w < 8; ++w) { sCarry[w] = g; g = sWaveTot[w] + A512 * g; }
    }
    __syncthreads();
    const float cprev = __shfl_up(cinc, 1, 64);
    const float Vin = (lane ? cprev : 0.0f)
                    + expf(-1.6f * (float)lane) * sCarry[wv];

    // --- replay chunk with true incoming V; first threshold crossing ---
    float V = Vin;
    int firstT = T_LEN;
    #pragma unroll
    for (int tt = 0; tt < 8; ++tt) {
        V = A * V + OMA * d[tt];
        if (V >= 1.0f && firstT == T_LEN) firstT = t0 + tt;
    }

    // --- block min-reduce ---
    #pragma unroll
    for (int o = 32; o > 0; o >>= 1)
        firstT = min(firstT, __shfl_xor(firstT, o, 64));
    if (lane == 0) sMin[wv] = firstT;
    __syncthreads();
    if (tid == 0) {
        int f = sMin[0];
        #pragma unroll
        for (int w = 1; w < 8; ++w) f = min(f, sMin[w]);
        const float lat   = (float)f;                          // T if never fired
        const float scale = fmaxf(latency_scale[0], 0.001f);
        out_lat[(b << 8) + c] = lat;
        out_act[(b << 8) + c] = expf(-lat / scale);
    }
}

// ---------------------------------------------------------------------------
// K2: gated mix + 2-layer MLP + softplus/clip. One 512-thread block per
// batch row. Mix phase reads precomputed ogT (coalesced over j), single
// serial fmaf chain per g-half preserving the previous accumulation order
// bitwise. W1/W2 phases: split reductions, 1-2 latency rounds each.
// Weights LLC-warm from the drive-phase warm-up blocks.
// ---------------------------------------------------------------------------
__global__ __launch_bounds__(512) void mlp_kernel(
    const float* __restrict__ act,
    const float* __restrict__ ogT, const float* __restrict__ bias,
    const float* __restrict__ W1, const float* __restrict__ b1,
    const float* __restrict__ W2, const float* __restrict__ b2,
    float* __restrict__ out_pred)
{
    const int b = blockIdx.x;
    const int t = threadIdx.x;
    const int j = t & 255;             // output index for og/W2 phases
    const int g = t >> 8;              // reduction group 0/1

    __shared__ float sAct[256];
    __shared__ float sP[2][256];       // og partials
    __shared__ float sMix[256];
    __shared__ float sPH[4][128];      // W1 partials
    __shared__ float sH[128];
    __shared__ float sPR[2][256];      // W2 partials

    if (t < 256) sAct[t] = act[b * 256 + t];
    __syncthreads();

    // mixed[j] = bias[j] + sum_i act[i]*og[j,i]; group g covers
    // i in [g*128, g*128+128). ogT[i*256+j] is coalesced over j.
    float mix = 0.0f;
    {
        const float* col = ogT + (size_t)(g * 128) * 256 + j;
        const float* a   = sAct + g * 128;
        #pragma unroll 16
        for (int ii = 0; ii < 128; ++ii)
            mix = fmaf(a[ii], col[ii * 256], mix);
    }
    sP[g][j] = mix;
    __syncthreads();
    if (t < 256) sMix[t] = bias[t] + sP[0][t] + sP[1][t];
    __syncthreads();

    // h[j1] = relu(b1 + sum_i mixed[i]*W1[i,j1]); 4 partials per j1, each a
    // fully-unrolled 64-load round. W1 (256,128) row-major: coalesced.
    {
        const int j1  = t & 127;
        const int seg = t >> 7;        // 0..3
        float h = 0.0f;
        #pragma unroll
        for (int ii = 0; ii < 64; ++ii) {
            const int i = seg * 64 + ii;
            h = fmaf(sMix[i], W1[i * 128 + j1], h);
        }
        sPH[seg][j1] = h;
    }
    __syncthreads();
    if (t < 128)
        sH[t] = fmaxf(b1[t] + ((sPH[0][t] + sPH[1][t]) + (sPH[2][t] + sPH[3][t])), 0.0f);
    __syncthreads();

    // raw[j] = b2[j] + sum_k h[k]*W2[k,j]; 2 partials per j, 64-load rounds.
    {
        float raw = 0.0f;
        #pragma unroll
        for (int kk = 0; kk < 64; ++kk) {
            const int k = g * 64 + kk;
            raw = fmaf(sH[k], W2[k * 256 + j], raw);
        }
        sPR[g][j] = raw;
    }
    __syncthreads();
    if (t < 256) {
        const float r  = b2[t] + sPR[0][t] + sPR[1][t];
        const float sp = fmaxf(r, 0.0f) + log1pf(expf(-fabsf(r)));
        out_pred[b * 256 + t] = fminf(fmaxf(sp, 0.0f), 4096.0f);
    }
}

// ---------------------------------------------------------------------------
extern "C" void kernel_launch(void* const* d_in, const int* in_sizes, int n_in,
                              void* d_out, int out_size, void* d_ws, size_t ws_size,
                              hipStream_t stream) {
    const float* x    = (const float*)d_in[0];
    const float* w3   = (const float*)d_in[1];
    const float* b3   = (const float*)d_in[2];
    const float* w5   = (const float*)d_in[3];
    const float* b5   = (const float*)d_in[4];
    const float* w9   = (const float*)d_in[5];
    const float* b9   = (const float*)d_in[6];
    const float* wred = (const float*)d_in[7];
    const float* bred = (const float*)d_in[8];
    const float* ls   = (const float*)d_in[9];
    const float* og   = (const float*)d_in[10];
    const float* bias = (const float*)d_in[11];
    const float* W1   = (const float*)d_in[12];
    const float* b1   = (const float*)d_in[13];
    const float* W2   = (const float*)d_in[14];
    const float* b2   = (const float*)d_in[15];

    float* ogT      = (float*)d_ws;           // 65536 floats (256KB)
    float* sink     = (float*)d_ws + 65536;   // prefetch sink (4096 floats)
    float* out      = (float*)d_out;
    float* out_pred = out;              // (8,256)
    float* out_lat  = out + 2048;       // (8,256)
    float* out_act  = out + 4096;       // (8,256)

    drive_scan_kernel<<<2056, 512, 0, stream>>>(
        x, w3, b3, w5, b5, w9, b9, wred, bred, ls,
        og, W1, W2, ogT, sink, out_lat, out_act);
    mlp_kernel<<<8, 512, 0, stream>>>(out_act, ogT, bias, W1, b1, W2, b2, out_pred);
}